// Round 10
// baseline (105.948 us; speedup 1.0000x reference)
//
#include <hip/hip_runtime.h>
#include <hip/hip_bf16.h>

#define N_TOK  1728     // 12*12*12
#define CDIM   64
#define NHEADS 32       // head_dim = 2
#define QTILES 27       // 1728 / 64
#define NPAIR  (N_TOK / 2)             // 864 fp16 key-pairs
#define SCALE  0.70710678118654752f    // 1/sqrt(2)
#define LOG2E  1.44269504088896340736f
#define JW     8                       // waves per attn block (j-split)
#define PCH    (NPAIR / JW)            // 108 key-pairs per wave

typedef _Float16 h2 __attribute__((ext_vector_type(2)));
union H2U { h2 h; unsigned int u; };

__device__ __forceinline__ unsigned int pack2(float a, float b) {
    H2U c; c.h.x = (_Float16)a; c.h.y = (_Float16)b; return c.u;
}
// q·k for one key: v_dot2_f32_f16 (fp32 accumulate) with compile-safe fallback
__device__ __forceinline__ float hdot2(unsigned int q, unsigned int k) {
    H2U a, b; a.u = q; b.u = k;
#if __has_builtin(__builtin_amdgcn_fdot2)
    return __builtin_amdgcn_fdot2(a.h, b.h, 0.0f, false);
#else
    return fmaf((float)a.h.x, (float)b.h.x, (float)a.h.y * (float)b.h.y);
#endif
}

// ---- dtype-adaptive load: f32=1 -> fp32 buffer, 0 -> bf16 buffer ----
__device__ __forceinline__ float ldin(const void* p, int i, int f32) {
    if (f32) return ((const float*)p)[i];
    union { unsigned int b; float f; } c;
    c.b = ((unsigned int)((const unsigned short*)p)[i]) << 16;
    return c.f;
}
// ---- wave-local dtype sniff (R1-proven: inputs are fp32 at runtime) ----
__device__ __forceinline__ int sniff_f32(const void* x) {
    union { unsigned int b; float f; } c;
    c.b = ((unsigned int)((const unsigned short*)x)[threadIdx.x & 63]) << 16;
    int bad = (((c.b >> 23) & 0xFF) == 0xFF) || (fabsf(c.f) > 1e10f);
    return (__ballot(bad) != 0ULL) ? 1 : 0;
}

// ========== Kernel 1: fused QKV + attention (R9 structure, fp16 KV) ==========
// grid 864 = 32 heads x 27 q-tiles, block 512 (8 waves).
// Staging identical to R9 (float4 x loads, scalar-pipe weights) but KV lands
// in LDS as fp16: KVh[p] = {K(2p),K(2p+1),V(2p),V(2p+1)} half2s = 16 B/2 keys
// -> attention does HALF the ds_read_b128s (LDS unit was the R9 bottleneck).
__global__ void __launch_bounds__(512, 4)
attn_fused(const void* __restrict__ xv, const void* __restrict__ wv,
           float* __restrict__ O) {
    __shared__ uint4 KVh[NPAIR];           // 13824 B
    __shared__ unsigned int Qs[64];        //   256 B  packed, pre-scaled q
    __shared__ float redbuf[JW * 64 * 3];  //  6144 B
    const int f    = sniff_f32(xv);
    const int tid  = threadIdx.x;
    const int lane = tid & 63;
    const int wav  = tid >> 6;
    const int h    = blockIdx.x / QTILES;
    const int t0   = (blockIdx.x % QTILES) * 64;

    if (f) {  // ---- fp32 staging (runtime-proven path) ----
        if (tid < 432) {
            const float* x   = (const float*)xv;
            const float* w   = (const float*)wv;
            const float* wq0 = w + (2 * h) * CDIM;       // uniform rows ->
            const float* wq1 = w + (2 * h + 1) * CDIM;   // scalar loads
            const float* wk0 = w + (64 + 2 * h) * CDIM;
            const float* wk1 = w + (65 + 2 * h) * CDIM;
            const float* wv0 = w + (128 + 2 * h) * CDIM;
            const float* wv1 = w + (129 + 2 * h) * CDIM;
            const int n0 = tid * 4;                      // tokens n0..n0+3
            const bool qd = (n0 & ~63) == t0;
            float k0[4] = {0,0,0,0}, k1[4] = {0,0,0,0};
            float v0[4] = {0,0,0,0}, v1[4] = {0,0,0,0};
            float q0[4] = {0,0,0,0}, q1[4] = {0,0,0,0};
            if (qd) {
#pragma unroll 4
                for (int c = 0; c < CDIM; ++c) {
                    const float4 xc = *(const float4*)(x + c * N_TOK + n0);
                    const float sk0 = wk0[c], sk1 = wk1[c];
                    const float sv0 = wv0[c], sv1 = wv1[c];
                    const float sq0 = wq0[c], sq1 = wq1[c];
                    const float xs[4] = {xc.x, xc.y, xc.z, xc.w};
#pragma unroll
                    for (int j = 0; j < 4; ++j) {
                        k0[j] = fmaf(xs[j], sk0, k0[j]);
                        k1[j] = fmaf(xs[j], sk1, k1[j]);
                        v0[j] = fmaf(xs[j], sv0, v0[j]);
                        v1[j] = fmaf(xs[j], sv1, v1[j]);
                        q0[j] = fmaf(xs[j], sq0, q0[j]);
                        q1[j] = fmaf(xs[j], sq1, q1[j]);
                    }
                }
            } else {
#pragma unroll 4
                for (int c = 0; c < CDIM; ++c) {
                    const float4 xc = *(const float4*)(x + c * N_TOK + n0);
                    const float sk0 = wk0[c], sk1 = wk1[c];
                    const float sv0 = wv0[c], sv1 = wv1[c];
                    const float xs[4] = {xc.x, xc.y, xc.z, xc.w};
#pragma unroll
                    for (int j = 0; j < 4; ++j) {
                        k0[j] = fmaf(xs[j], sk0, k0[j]);
                        k1[j] = fmaf(xs[j], sk1, k1[j]);
                        v0[j] = fmaf(xs[j], sv0, v0[j]);
                        v1[j] = fmaf(xs[j], sv1, v1[j]);
                    }
                }
            }
            // pairs 2t (tokens n0,n0+1) and 2t+1 (tokens n0+2,n0+3)
            KVh[2 * tid]     = make_uint4(pack2(k0[0], k1[0]), pack2(k0[1], k1[1]),
                                          pack2(v0[0], v1[0]), pack2(v0[1], v1[1]));
            KVh[2 * tid + 1] = make_uint4(pack2(k0[2], k1[2]), pack2(k0[3], k1[3]),
                                          pack2(v0[2], v1[2]), pack2(v0[3], v1[3]));
            if (qd) {
#pragma unroll
                for (int j = 0; j < 4; ++j)
                    Qs[n0 + j - t0] = pack2(q0[j] * (SCALE * LOG2E),
                                            q1[j] * (SCALE * LOG2E));
            }
        }
    } else {  // ---- generic bf16 fallback (never observed at runtime) ----
        unsigned int* KVu = (unsigned int*)KVh;
        for (int n = tid; n < N_TOK; n += 512) {
            float k0 = 0, k1 = 0, v0 = 0, v1 = 0, q0 = 0, q1 = 0;
            for (int c = 0; c < CDIM; ++c) {
                float xc = ldin(xv, c * N_TOK + n, 0);
                q0 = fmaf(xc, ldin(wv, (2 * h) * CDIM + c, 0), q0);
                q1 = fmaf(xc, ldin(wv, (2 * h + 1) * CDIM + c, 0), q1);
                k0 = fmaf(xc, ldin(wv, (64 + 2 * h) * CDIM + c, 0), k0);
                k1 = fmaf(xc, ldin(wv, (65 + 2 * h) * CDIM + c, 0), k1);
                v0 = fmaf(xc, ldin(wv, (128 + 2 * h) * CDIM + c, 0), v0);
                v1 = fmaf(xc, ldin(wv, (129 + 2 * h) * CDIM + c, 0), v1);
            }
            KVu[(n >> 1) * 4 + (n & 1)]     = pack2(k0, k1);
            KVu[(n >> 1) * 4 + 2 + (n & 1)] = pack2(v0, v1);
            if ((n & ~63) == t0)
                Qs[n - t0] = pack2(q0 * (SCALE * LOG2E), q1 * (SCALE * LOG2E));
        }
    }
    __syncthreads();

    // ---- attention: 108 b128 reads/wave (2 keys each), 4-deep batches ----
    const unsigned int qh = Qs[lane];
    const uint4* KVp = &KVh[wav * PCH];
    float la = 0.f, lb = 0.f, oa0 = 0.f, oa1 = 0.f, ob0 = 0.f, ob1 = 0.f;
    for (int g = 0; g < PCH; g += 4) {   // 27 groups of 4 uint4 = 8 keys
        uint4 d[4];
#pragma unroll
        for (int u = 0; u < 4; ++u) d[u] = KVp[g + u];   // 4 reads in flight
#pragma unroll
        for (int u = 0; u < 4; ++u) {
            H2U va, vb; va.u = d[u].z; vb.u = d[u].w;
            float ea = __builtin_amdgcn_exp2f(hdot2(qh, d[u].x));
            float eb = __builtin_amdgcn_exp2f(hdot2(qh, d[u].y));
            la += ea; lb += eb;
            oa0 = fmaf(ea, (float)va.h.x, oa0);
            oa1 = fmaf(ea, (float)va.h.y, oa1);
            ob0 = fmaf(eb, (float)vb.h.x, ob0);
            ob1 = fmaf(eb, (float)vb.h.y, ob1);
        }
    }
    float* red = redbuf + wav * 192 + lane * 3;   // stride-3: <=2-way (free)
    red[0] = la + lb; red[1] = oa0 + ob0; red[2] = oa1 + ob1;
    __syncthreads();
    if (wav == 0) {
        float L = 0.f, A = 0.f, B = 0.f;
#pragma unroll
        for (int w = 0; w < JW; ++w) {
            const float* r = redbuf + w * 192 + lane * 3;
            L += r[0]; A += r[1]; B += r[2];
        }
        float inv = 1.0f / L;
        int n = t0 + lane;
        *((float2*)(O + n * CDIM + 2 * h)) = make_float2(A * inv, B * inv);
    }
}

// ========== Kernel 2: output projection (R9-proven, unchanged) ==========
__global__ void __launch_bounds__(256)
proj_kernel(const void* __restrict__ xv,   // dtype sniff only
            const float* __restrict__ O,
            const void* __restrict__ w_proj, const void* __restrict__ b_proj,
            void* __restrict__ out) {
    __shared__ float Ws[CDIM * 65];        // 16640 B
    const int f    = sniff_f32(xv);
    const int tid  = threadIdx.x;
    const int lane = tid & 63;
    const int wav  = tid >> 6;
    for (int e = tid; e < CDIM * CDIM; e += 256)    // e = co*64+ci, coalesced
        Ws[(e & 63) * 65 + (e >> 6)] = ldin(w_proj, e, f);
    __syncthreads();
    int n = blockIdx.x * 4 + wav;          // 432*4 = 1728
    float acc = ldin(b_proj, lane, f);
#pragma unroll 8
    for (int ci = 0; ci < CDIM; ++ci)
        acc = fmaf(O[n * CDIM + ci],                 // uniform -> s_load
                   Ws[ci * 65 + lane], acc);          // bank-conflict-free
    if (f) ((float*)out)[n * CDIM + lane] = acc;
    else   ((__hip_bfloat16*)out)[n * CDIM + lane] = __float2bfloat16(acc);
}

extern "C" void kernel_launch(void* const* d_in, const int* in_sizes, int n_in,
                              void* d_out, int out_size, void* d_ws, size_t ws_size,
                              hipStream_t stream) {
    const void* x      = d_in[0];
    const void* w_qkv  = d_in[1];
    const void* w_proj = d_in[2];
    const void* b_proj = d_in[3];

    float* O = (float*)d_ws;   // [1728][64] fp32, 442368 B (ws >= 1.77 MB proven)

    attn_fused <<<NHEADS * QTILES, 512, 0, stream>>>(x, w_qkv, O);
    proj_kernel<<<432, 256, 0, stream>>>(x, O, w_proj, b_proj, d_out);
}

// Round 11
// 94.678 us; speedup vs baseline: 1.1190x; 1.1190x over previous
//
#include <hip/hip_runtime.h>
#include <hip/hip_bf16.h>

#define N_TOK  1728     // 12*12*12
#define CDIM   64
#define NHEADS 32       // head_dim = 2
#define QTILES 27       // 1728 / 64
#define NPAIR  (N_TOK / 2)             // 864 fp16 key-pairs per head
#define SCALE  0.70710678118654752f    // 1/sqrt(2)
#define LOG2E  1.44269504088896340736f
#define JW     8                       // waves per attn block (j-split)
#define PCH    (NPAIR / JW)            // 108 key-pairs per wave

typedef _Float16 h2 __attribute__((ext_vector_type(2)));
union H2U { h2 h; unsigned int u; };

__device__ __forceinline__ unsigned int pack2(float a, float b) {
    H2U c; c.h.x = (_Float16)a; c.h.y = (_Float16)b; return c.u;
}
// q·k: v_dot2_f32_f16 (fp32 accumulate) with compile-safe fallback
__device__ __forceinline__ float hdot2(unsigned int q, unsigned int k) {
    H2U a, b; a.u = q; b.u = k;
#if __has_builtin(__builtin_amdgcn_fdot2)
    return __builtin_amdgcn_fdot2(a.h, b.h, 0.0f, false);
#else
    return fmaf((float)a.h.x, (float)b.h.x, (float)a.h.y * (float)b.h.y);
#endif
}

// ---- dtype-adaptive load: f32=1 -> fp32 buffer, 0 -> bf16 buffer ----
__device__ __forceinline__ float ldin(const void* p, int i, int f32) {
    if (f32) return ((const float*)p)[i];
    union { unsigned int b; float f; } c;
    c.b = ((unsigned int)((const unsigned short*)p)[i]) << 16;
    return c.f;
}
// ---- wave-local dtype sniff (R1-proven: inputs are fp32 at runtime) ----
__device__ __forceinline__ int sniff_f32(const void* x) {
    union { unsigned int b; float f; } c;
    c.b = ((unsigned int)((const unsigned short*)x)[threadIdx.x & 63]) << 16;
    int bad = (((c.b >> 23) & 0xFF) == 0xFF) || (fabsf(c.f) > 1e10f);
    return (__ballot(bad) != 0ULL) ? 1 : 0;
}

// ========== Kernel 1: QKV -> packed fp16 Q / KV in ws (computed ONCE) ==========
// grid (27, 96), block 64. y -> (h = y&31, which = y>>5 in {q,k,v}).
// Each wave computes BOTH rows (2h, 2h+1) of its section for 64 tokens:
// x reads coalesced over lanes, weight rows wave-uniform -> scalar pipe.
// Layouts (match attn kernel):
//   Qp[h*N_TOK + n]                       = pack(q0*s, q1*s)
//   KVg[(h*NPAIR + n/2)*4 + (n&1)]        = pack(k0, k1)   (uint view)
//   KVg[(h*NPAIR + n/2)*4 + 2 + (n&1)]    = pack(v0, v1)
__global__ void __launch_bounds__(64)
qkv_pack(const void* __restrict__ xv, const void* __restrict__ wv,
         unsigned int* __restrict__ Qp, unsigned int* __restrict__ KVg) {
    const int f     = sniff_f32(xv);
    const int lane  = threadIdx.x;
    const int h     = blockIdx.y & 31;
    const int which = blockIdx.y >> 5;
    const int r0    = (which << 6) + 2 * h;        // uniform -> s_loads
    const int n     = blockIdx.x * 64 + lane;
    float a0 = 0.f, a1 = 0.f;
    if (f) {
        const float* x  = (const float*)xv;
        const float* w0 = (const float*)wv + r0 * CDIM;
        const float* w1 = w0 + CDIM;
#pragma unroll 8
        for (int c = 0; c < CDIM; ++c) {
            float xc = x[c * N_TOK + n];           // coalesced
            a0 = fmaf(xc, w0[c], a0);
            a1 = fmaf(xc, w1[c], a1);
        }
    } else {
#pragma unroll 8
        for (int c = 0; c < CDIM; ++c) {
            float xc = ldin(xv, c * N_TOK + n, 0);
            a0 = fmaf(xc, ldin(wv, r0 * CDIM + c, 0), a0);
            a1 = fmaf(xc, ldin(wv, (r0 + 1) * CDIM + c, 0), a1);
        }
    }
    if (which == 0)
        Qp[h * N_TOK + n] = pack2(a0 * (SCALE * LOG2E), a1 * (SCALE * LOG2E));
    else
        KVg[(h * NPAIR + (n >> 1)) * 4 + ((which == 1) ? 0 : 2) + (n & 1)] =
            pack2(a0, a1);
}

// ========== Kernel 2: attention (stages 13.8 KB head-KV from L2) ==========
// grid (27, 32), block 512 (8 waves). LDS writes: linear tid, 16 B stride
// (R9-proven conflict-free). Inner loop: 4 independent accumulator chains.
__global__ void __launch_bounds__(512, 4)
attn_kernel(const unsigned int* __restrict__ Qp, const uint4* __restrict__ KVg,
            float* __restrict__ O) {
    __shared__ uint4 KVs[NPAIR];           // 13824 B
    __shared__ float redbuf[JW * 64 * 3];  //  6144 B
    const int tid  = threadIdx.x;
    const int lane = tid & 63;
    const int wav  = tid >> 6;
    const int h    = blockIdx.y;
    const int t0   = blockIdx.x * 64;

    const uint4* src = KVg + h * NPAIR;
    KVs[tid] = src[tid];                               // 512 coalesced b128
    if (tid < NPAIR - 512) KVs[512 + tid] = src[512 + tid];   // +352
    const unsigned int qh = Qp[h * N_TOK + t0 + lane]; // coalesced dword
    __syncthreads();

    // 216 keys/wave as 108 uint4 (2 keys each); 4 chains for stall-hiding
    const uint4* KVp = &KVs[wav * PCH];
    float l0 = 0.f, l1 = 0.f, l2 = 0.f, l3 = 0.f;
    float p0 = 0.f, p1 = 0.f, p2 = 0.f, p3 = 0.f;   // o-dim 0 partials
    float s0 = 0.f, s1 = 0.f, s2 = 0.f, s3 = 0.f;   // o-dim 1 partials
    for (int g = 0; g < PCH; g += 4) {     // 27 iterations
        uint4 d0 = KVp[g], d1 = KVp[g + 1], d2 = KVp[g + 2], d3 = KVp[g + 3];
        H2U v;
        float ea, eb;
        ea = __builtin_amdgcn_exp2f(hdot2(qh, d0.x));
        eb = __builtin_amdgcn_exp2f(hdot2(qh, d0.y));
        v.u = d0.z; l0 += ea; p0 = fmaf(ea, (float)v.h.x, p0); s0 = fmaf(ea, (float)v.h.y, s0);
        v.u = d0.w; l0 += eb; p0 = fmaf(eb, (float)v.h.x, p0); s0 = fmaf(eb, (float)v.h.y, s0);
        ea = __builtin_amdgcn_exp2f(hdot2(qh, d1.x));
        eb = __builtin_amdgcn_exp2f(hdot2(qh, d1.y));
        v.u = d1.z; l1 += ea; p1 = fmaf(ea, (float)v.h.x, p1); s1 = fmaf(ea, (float)v.h.y, s1);
        v.u = d1.w; l1 += eb; p1 = fmaf(eb, (float)v.h.x, p1); s1 = fmaf(eb, (float)v.h.y, s1);
        ea = __builtin_amdgcn_exp2f(hdot2(qh, d2.x));
        eb = __builtin_amdgcn_exp2f(hdot2(qh, d2.y));
        v.u = d2.z; l2 += ea; p2 = fmaf(ea, (float)v.h.x, p2); s2 = fmaf(ea, (float)v.h.y, s2);
        v.u = d2.w; l2 += eb; p2 = fmaf(eb, (float)v.h.x, p2); s2 = fmaf(eb, (float)v.h.y, s2);
        ea = __builtin_amdgcn_exp2f(hdot2(qh, d3.x));
        eb = __builtin_amdgcn_exp2f(hdot2(qh, d3.y));
        v.u = d3.z; l3 += ea; p3 = fmaf(ea, (float)v.h.x, p3); s3 = fmaf(ea, (float)v.h.y, s3);
        v.u = d3.w; l3 += eb; p3 = fmaf(eb, (float)v.h.x, p3); s3 = fmaf(eb, (float)v.h.y, s3);
    }
    float* red = redbuf + wav * 192 + lane * 3;   // stride-3: <=2-way (free)
    red[0] = (l0 + l1) + (l2 + l3);
    red[1] = (p0 + p1) + (p2 + p3);
    red[2] = (s0 + s1) + (s2 + s3);
    __syncthreads();
    if (wav == 0) {
        float L = 0.f, A = 0.f, B = 0.f;
#pragma unroll
        for (int w = 0; w < JW; ++w) {
            const float* r = redbuf + w * 192 + lane * 3;
            L += r[0]; A += r[1]; B += r[2];
        }
        float inv = 1.0f / L;
        int n = t0 + lane;
        *((float2*)(O + n * CDIM + 2 * h)) = make_float2(A * inv, B * inv);
    }
}

// ========== Kernel 3: output projection (R9-proven, unchanged) ==========
__global__ void __launch_bounds__(256)
proj_kernel(const void* __restrict__ xv,   // dtype sniff only
            const float* __restrict__ O,
            const void* __restrict__ w_proj, const void* __restrict__ b_proj,
            void* __restrict__ out) {
    __shared__ float Ws[CDIM * 65];        // 16640 B
    const int f    = sniff_f32(xv);
    const int tid  = threadIdx.x;
    const int lane = tid & 63;
    const int wav  = tid >> 6;
    for (int e = tid; e < CDIM * CDIM; e += 256)    // e = co*64+ci, coalesced
        Ws[(e & 63) * 65 + (e >> 6)] = ldin(w_proj, e, f);
    __syncthreads();
    int n = blockIdx.x * 4 + wav;          // 432*4 = 1728
    float acc = ldin(b_proj, lane, f);
#pragma unroll 8
    for (int ci = 0; ci < CDIM; ++ci)
        acc = fmaf(O[n * CDIM + ci],                 // uniform -> s_load
                   Ws[ci * 65 + lane], acc);          // bank-conflict-free
    if (f) ((float*)out)[n * CDIM + lane] = acc;
    else   ((__hip_bfloat16*)out)[n * CDIM + lane] = __float2bfloat16(acc);
}

extern "C" void kernel_launch(void* const* d_in, const int* in_sizes, int n_in,
                              void* d_out, int out_size, void* d_ws, size_t ws_size,
                              hipStream_t stream) {
    const void* x      = d_in[0];
    const void* w_qkv  = d_in[1];
    const void* w_proj = d_in[2];
    const void* b_proj = d_in[3];

    // ws layout (1.106 MB of the proven >=1.77 MB):
    float*        O   = (float*)d_ws;                    // 442368 B [1728][64]
    unsigned int* Qp  = (unsigned int*)(O + N_TOK * CDIM);       // 221184 B
    unsigned int* KVg = Qp + NHEADS * N_TOK;                     // 442368 B

    qkv_pack   <<<dim3(QTILES, 96), 64, 0, stream>>>(x, w_qkv, Qp, KVg);
    attn_kernel<<<dim3(QTILES, NHEADS), 512, 0, stream>>>(Qp, (const uint4*)KVg, O);
    proj_kernel<<<432, 256, 0, stream>>>(x, O, w_proj, b_proj, d_out);
}

// Round 12
// 93.148 us; speedup vs baseline: 1.1374x; 1.0164x over previous
//
#include <hip/hip_runtime.h>
#include <hip/hip_bf16.h>

#define N_TOK  1728     // 12*12*12
#define CDIM   64
#define NHEADS 32       // head_dim = 2
#define QTILES 27       // 1728 / 64
#define NPAIR  (N_TOK / 2)             // 864 fp16 key-pairs per head
#define SCALE  0.70710678118654752f    // 1/sqrt(2)
#define LOG2E  1.44269504088896340736f
#define JW     8                       // waves per attn block (j-split)
#define PCH    (NPAIR / JW)            // 108 key-pairs per wave

typedef _Float16 h2 __attribute__((ext_vector_type(2)));
union H2U { h2 h; unsigned int u; };

__device__ __forceinline__ unsigned int pack2(float a, float b) {
    H2U c; c.h.x = (_Float16)a; c.h.y = (_Float16)b; return c.u;
}
// q·k: v_dot2_f32_f16 (fp32 accumulate) with compile-safe fallback
__device__ __forceinline__ float hdot2(unsigned int q, unsigned int k) {
    H2U a, b; a.u = q; b.u = k;
#if __has_builtin(__builtin_amdgcn_fdot2)
    return __builtin_amdgcn_fdot2(a.h, b.h, 0.0f, false);
#else
    return fmaf((float)a.h.x, (float)b.h.x, (float)a.h.y * (float)b.h.y);
#endif
}

// ---- dtype-adaptive load: f32=1 -> fp32 buffer, 0 -> bf16 buffer ----
__device__ __forceinline__ float ldin(const void* p, int i, int f32) {
    if (f32) return ((const float*)p)[i];
    union { unsigned int b; float f; } c;
    c.b = ((unsigned int)((const unsigned short*)p)[i]) << 16;
    return c.f;
}
// ---- wave-local dtype sniff (R1-proven: inputs are fp32 at runtime) ----
__device__ __forceinline__ int sniff_f32(const void* x) {
    union { unsigned int b; float f; } c;
    c.b = ((unsigned int)((const unsigned short*)x)[threadIdx.x & 63]) << 16;
    int bad = (((c.b >> 23) & 0xFF) == 0xFF) || (fabsf(c.f) > 1e10f);
    return (__ballot(bad) != 0ULL) ? 1 : 0;
}

// ========== Kernel 1: QKV -> packed fp16 Q / KV in ws (computed ONCE) ==========
// grid (27, 96), block 64. y -> (h = y&31, which = y>>5 in {q,k,v}).
// x reads coalesced over lanes, weight rows wave-uniform -> scalar pipe.
__global__ void __launch_bounds__(64)
qkv_pack(const void* __restrict__ xv, const void* __restrict__ wv,
         unsigned int* __restrict__ Qp, unsigned int* __restrict__ KVg) {
    const int f     = sniff_f32(xv);
    const int lane  = threadIdx.x;
    const int h     = blockIdx.y & 31;
    const int which = blockIdx.y >> 5;
    const int r0    = (which << 6) + 2 * h;        // uniform -> s_loads
    const int n     = blockIdx.x * 64 + lane;
    float a0 = 0.f, a1 = 0.f;
    if (f) {
        const float* x  = (const float*)xv;
        const float* w0 = (const float*)wv + r0 * CDIM;
        const float* w1 = w0 + CDIM;
#pragma unroll 8
        for (int c = 0; c < CDIM; ++c) {
            float xc = x[c * N_TOK + n];           // coalesced
            a0 = fmaf(xc, w0[c], a0);
            a1 = fmaf(xc, w1[c], a1);
        }
    } else {
#pragma unroll 8
        for (int c = 0; c < CDIM; ++c) {
            float xc = ldin(xv, c * N_TOK + n, 0);
            a0 = fmaf(xc, ldin(wv, r0 * CDIM + c, 0), a0);
            a1 = fmaf(xc, ldin(wv, (r0 + 1) * CDIM + c, 0), a1);
        }
    }
    if (which == 0)
        Qp[h * N_TOK + n] = pack2(a0 * (SCALE * LOG2E), a1 * (SCALE * LOG2E));
    else
        KVg[(h * NPAIR + (n >> 1)) * 4 + ((which == 1) ? 0 : 2) + (n & 1)] =
            pack2(a0, a1);
}

// ========== Kernel 2: attention — software-pipelined inner loop ==========
// grid (27, 32), block 512 (8 waves). Stages 13.8 KB head-KV from L2 into
// LDS (16 B-stride writes, R9-proven conflict-free), then each wave streams
// its 108 uint4 with a register double-buffer: batch g+1's 4 ds_read_b128
// issue BEFORE batch g's compute, hiding ~120 cyc LDS latency behind ~80 cyc
// of compute + co-resident waves. 4 independent accumulator chains.
__global__ void __launch_bounds__(512, 4)
attn_kernel(const unsigned int* __restrict__ Qp, const uint4* __restrict__ KVg,
            float* __restrict__ O) {
    __shared__ uint4 KVs[NPAIR];           // 13824 B
    __shared__ float redbuf[JW * 64 * 3];  //  6144 B
    const int tid  = threadIdx.x;
    const int lane = tid & 63;
    const int wav  = tid >> 6;
    const int h    = blockIdx.y;
    const int t0   = blockIdx.x * 64;

    const uint4* src = KVg + h * NPAIR;
    KVs[tid] = src[tid];                               // 512 coalesced b128
    if (tid < NPAIR - 512) KVs[512 + tid] = src[512 + tid];   // +352
    const unsigned int qh = Qp[h * N_TOK + t0 + lane]; // coalesced dword
    __syncthreads();

    const uint4* KVp = &KVs[wav * PCH];
    float l0 = 0.f, l1 = 0.f, l2 = 0.f, l3 = 0.f;
    float p0 = 0.f, p1 = 0.f, p2 = 0.f, p3 = 0.f;   // o-dim 0 partials
    float s0 = 0.f, s1 = 0.f, s2 = 0.f, s3 = 0.f;   // o-dim 1 partials
    uint4 c0 = KVp[0], c1 = KVp[1], c2 = KVp[2], c3 = KVp[3];
#pragma unroll
    for (int g = 0; g < PCH; g += 4) {     // 27 iterations, fully unrolled
        const int gn = (g + 4 < PCH) ? g + 4 : 0;   // clamped prefetch
        uint4 n0 = KVp[gn], n1 = KVp[gn + 1], n2 = KVp[gn + 2], n3 = KVp[gn + 3];
        H2U v;
        float ea, eb;
        ea = __builtin_amdgcn_exp2f(hdot2(qh, c0.x));
        eb = __builtin_amdgcn_exp2f(hdot2(qh, c0.y));
        l0 += ea + eb;
        v.u = c0.z; p0 = fmaf(ea, (float)v.h.x, p0); s0 = fmaf(ea, (float)v.h.y, s0);
        v.u = c0.w; p0 = fmaf(eb, (float)v.h.x, p0); s0 = fmaf(eb, (float)v.h.y, s0);
        ea = __builtin_amdgcn_exp2f(hdot2(qh, c1.x));
        eb = __builtin_amdgcn_exp2f(hdot2(qh, c1.y));
        l1 += ea + eb;
        v.u = c1.z; p1 = fmaf(ea, (float)v.h.x, p1); s1 = fmaf(ea, (float)v.h.y, s1);
        v.u = c1.w; p1 = fmaf(eb, (float)v.h.x, p1); s1 = fmaf(eb, (float)v.h.y, s1);
        ea = __builtin_amdgcn_exp2f(hdot2(qh, c2.x));
        eb = __builtin_amdgcn_exp2f(hdot2(qh, c2.y));
        l2 += ea + eb;
        v.u = c2.z; p2 = fmaf(ea, (float)v.h.x, p2); s2 = fmaf(ea, (float)v.h.y, s2);
        v.u = c2.w; p2 = fmaf(eb, (float)v.h.x, p2); s2 = fmaf(eb, (float)v.h.y, s2);
        ea = __builtin_amdgcn_exp2f(hdot2(qh, c3.x));
        eb = __builtin_amdgcn_exp2f(hdot2(qh, c3.y));
        l3 += ea + eb;
        v.u = c3.z; p3 = fmaf(ea, (float)v.h.x, p3); s3 = fmaf(ea, (float)v.h.y, s3);
        v.u = c3.w; p3 = fmaf(eb, (float)v.h.x, p3); s3 = fmaf(eb, (float)v.h.y, s3);
        c0 = n0; c1 = n1; c2 = n2; c3 = n3;
    }
    float* red = redbuf + wav * 192 + lane * 3;   // stride-3: <=2-way (free)
    red[0] = (l0 + l1) + (l2 + l3);
    red[1] = (p0 + p1) + (p2 + p3);
    red[2] = (s0 + s1) + (s2 + s3);
    __syncthreads();
    if (wav == 0) {
        float L = 0.f, A = 0.f, B = 0.f;
#pragma unroll
        for (int w = 0; w < JW; ++w) {
            const float* r = redbuf + w * 192 + lane * 3;
            L += r[0]; A += r[1]; B += r[2];
        }
        float inv = 1.0f / L;
        int n = t0 + lane;
        *((float2*)(O + n * CDIM + 2 * h)) = make_float2(A * inv, B * inv);
    }
}

// ========== Kernel 3: output projection (R9-proven, unchanged) ==========
__global__ void __launch_bounds__(256)
proj_kernel(const void* __restrict__ xv,   // dtype sniff only
            const float* __restrict__ O,
            const void* __restrict__ w_proj, const void* __restrict__ b_proj,
            void* __restrict__ out) {
    __shared__ float Ws[CDIM * 65];        // 16640 B
    const int f    = sniff_f32(xv);
    const int tid  = threadIdx.x;
    const int lane = tid & 63;
    const int wav  = tid >> 6;
    for (int e = tid; e < CDIM * CDIM; e += 256)    // e = co*64+ci, coalesced
        Ws[(e & 63) * 65 + (e >> 6)] = ldin(w_proj, e, f);
    __syncthreads();
    int n = blockIdx.x * 4 + wav;          // 432*4 = 1728
    float acc = ldin(b_proj, lane, f);
#pragma unroll 8
    for (int ci = 0; ci < CDIM; ++ci)
        acc = fmaf(O[n * CDIM + ci],                 // uniform -> s_load
                   Ws[ci * 65 + lane], acc);          // bank-conflict-free
    if (f) ((float*)out)[n * CDIM + lane] = acc;
    else   ((__hip_bfloat16*)out)[n * CDIM + lane] = __float2bfloat16(acc);
}

extern "C" void kernel_launch(void* const* d_in, const int* in_sizes, int n_in,
                              void* d_out, int out_size, void* d_ws, size_t ws_size,
                              hipStream_t stream) {
    const void* x      = d_in[0];
    const void* w_qkv  = d_in[1];
    const void* w_proj = d_in[2];
    const void* b_proj = d_in[3];

    // ws layout (1.106 MB of the proven >=1.77 MB):
    float*        O   = (float*)d_ws;                    // 442368 B [1728][64]
    unsigned int* Qp  = (unsigned int*)(O + N_TOK * CDIM);       // 221184 B
    unsigned int* KVg = Qp + NHEADS * N_TOK;                     // 442368 B

    qkv_pack   <<<dim3(QTILES, 96), 64, 0, stream>>>(x, w_qkv, Qp, KVg);
    attn_kernel<<<dim3(QTILES, NHEADS), 512, 0, stream>>>(Qp, (const uint4*)KVg, O);
    proj_kernel<<<432, 256, 0, stream>>>(x, O, w_proj, b_proj, d_out);
}